// Round 2
// baseline (198.990 us; speedup 1.0000x reference)
//
#include <hip/hip_runtime.h>

// PatchEmbeder v3 (resubmit — round 1 was an infra failure, no HW data):
// collapse W1@W2 -> W12 [768x64] (exact: no nonlinearity), fold b12 = b1@W2+b2
// through W3 into the posb table. Main kernel becomes 2 GEMM stages
// (K=768 -> 64, then K=64 -> 768) with ONE barrier and no H2 LDS round trip.
// v2b was latency-serialized (VGPR=40, wave lifetime ~46us, VALUBusy 8%):
// here loads are explicitly batched (12 X-float4 up front; phase-3 w3t/posb in
// 2-deep double-buffered groups of 3 col-tiles, first group prefetched before
// the phase-2 LDS reduce) and __launch_bounds__(256,4) gives the allocator a
// 128-VGPR budget so the batches stay in flight.

#define BATCH 128
#define CH    3
#define NP    196
#define PIX   256          // 16*16
#define K1    768          // CH*PIX
#define NH    64           // collapsed hidden width (W12 cols)
#define EMB   768

typedef __bf16 bf16x8 __attribute__((ext_vector_type(8)));
typedef float  f32x4  __attribute__((ext_vector_type(4)));

// workspace byte offsets (16B aligned)
#define W12T_OFF 0                       // [64][768] bf16 = 98304
#define W3T_OFF  98304                   // [768][64] bf16 = 98304
#define B12_OFF  196608                  // [64] f32 = 256
#define POSB_OFF 196864                  // [197][768] f32 = 605184 -> end 802048

// ---------------------------------------------------------------------------
// prep1: w12t[n][k] = (W1@W2)^T in bf16; b12 = b1@W2 + b2 (f32)
// ---------------------------------------------------------------------------
__global__ __launch_bounds__(256) void patchembed_prep1(
    const float* __restrict__ W1, const float* __restrict__ W2,
    const float* __restrict__ b1, const float* __restrict__ b2,
    __bf16* __restrict__ w12t, float* __restrict__ b12)
{
    const int i = blockIdx.x * 256 + threadIdx.x;
    if (i < NH * K1) {                 // i = n*768 + k
        const int n = i / K1, k = i - n * K1;
        float s = 0.f;
        #pragma unroll
        for (int j = 0; j < 32; ++j) s += W1[k * 32 + j] * W2[j * NH + n];
        w12t[i] = (__bf16)s;
    } else if (i < NH * K1 + NH) {
        const int n = i - NH * K1;
        float s = b2[n];
        #pragma unroll
        for (int j = 0; j < 32; ++j) s += b1[j] * W2[j * NH + n];
        b12[n] = s;
    }
}

// ---------------------------------------------------------------------------
// prep2: w3t transpose; posb[r][c] = pos + (r==0 ? cls : b3 + b12@W3); cls rows
// ---------------------------------------------------------------------------
__global__ __launch_bounds__(256) void patchembed_prep2(
    const float* __restrict__ W3, const float* __restrict__ b3,
    const float* __restrict__ cls, const float* __restrict__ pos,
    const float* __restrict__ b12,
    __bf16* __restrict__ w3t, float* __restrict__ posb, float* __restrict__ out)
{
    const int i = blockIdx.x * 256 + threadIdx.x;
    const int T1 = EMB * NH;           // 49152
    const int T2 = T1 + 197 * EMB;     // 200448
    const int T3 = T2 + BATCH * EMB;   // 298752
    if (i < T1) {                      // w3t[col][kk] = W3[kk][col]
        const int col = i >> 6, kk = i & 63;
        w3t[i] = (__bf16)W3[kk * EMB + col];
    } else if (i < T2) {
        const int j = i - T1;
        const int r = j / EMB, c = j - r * EMB;
        float v = pos[j];
        if (r == 0) {
            v += cls[c];               // row 0 never read by main; harmless
        } else {
            float s = b3[c];           // fold (b1@W2+b2)@W3 + b3 into the table
            #pragma unroll
            for (int n = 0; n < NH; ++n) s += b12[n] * W3[n * EMB + c];
            v += s;
        }
        posb[j] = v;
    } else if (i < T3) {               // out[b][0][c] = cls + pos[0]
        const int j = i - T2;
        const int b = j / EMB, c = j - b * EMB;
        out[b * (197 * EMB) + c] = cls[c] + pos[c];
    }
}

// ---------------------------------------------------------------------------
// main: 16 rows/block, 4 waves.
//  phase1: stage-1 mm (x @ W12), K-split: wave wv does ksteps [wv*6, wv*6+6),
//          N=64 -> 4 n-tiles/wave; all 12 X float4 loads issued up front.
//          partials -> LDS f32.
//  phase2: 4-way reduce straight into stage-2 A-fragments (no mm2, no H2 LDS).
//  phase3: stage-2 mm (h2 @ W3), cols split 4-ways/wave (192 each); w3t+posb
//          loads double-buffered in groups of 3 col-tiles; group 0 prefetched
//          BEFORE the phase-2 reduce (independent of LDS).
// MFMA 16x16x32 bf16 layouts (verified m89/m120):
//   A: m = lane&15, k = (lane>>4)*8 + j
//   B: n = lane&15, k = (lane>>4)*8 + j
//   C: col = lane&15, row = (lane>>4)*4 + reg
// ---------------------------------------------------------------------------
__global__ __launch_bounds__(256, 4) void patchembed_main(
    const float* __restrict__ X,      // [B][C][P][256] fp32
    const __bf16* __restrict__ w12t,  // [64][768]
    const __bf16* __restrict__ w3t,   // [768][64]
    const float*  __restrict__ posb,  // [197][768]
    float* __restrict__ out)          // [B][197][768]
{
    __shared__ __align__(16) float h1p[4][16][68];  // 17408 B (pad: ~8-way on
                                                    // phase-2 read, 16 reads/thr
                                                    // total — immaterial)

    const int tid  = threadIdx.x;
    const int wv   = tid >> 6;
    const int lane = tid & 63;
    const int l15  = lane & 15;
    const int q    = lane >> 4;
    const int r0   = blockIdx.x * 16;

    // output row bases (phase 3) — computed early, off the critical path
    int obase[4], pbase[4];
    #pragma unroll
    for (int r = 0; r < 4; ++r) {
        const int row = r0 + q * 4 + r;
        const int b = row / NP, p = row - b * NP;
        obase[r] = (b * 197 + p + 1) * EMB;
        pbase[r] = (p + 1) * EMB;
    }

    // ---------------- phase 1
    {
        const int xrow = r0 + l15;
        const int b = xrow / NP, p = xrow - b * NP;
        const float* xb = X + ((b * CH) * NP + p) * PIX;
        const int kb0 = wv * 6;

        float4 u[6], v[6];                       // 12 loads in flight (48 VGPR)
        #pragma unroll
        for (int t = 0; t < 6; ++t) {
            const int kb = kb0 + t;
            const float* ptr = xb + (kb >> 3) * (NP * PIX) + (kb & 7) * 32 + q * 8;
            u[t] = *(const float4*)ptr;
            v[t] = *(const float4*)(ptr + 4);
        }

        f32x4 acc0 = {0.f, 0.f, 0.f, 0.f};
        f32x4 acc1 = acc0, acc2 = acc0, acc3 = acc0;
        #pragma unroll
        for (int t = 0; t < 6; ++t) {
            const int kb = kb0 + t;
            bf16x8 a;
            a[0] = (__bf16)u[t].x; a[1] = (__bf16)u[t].y;
            a[2] = (__bf16)u[t].z; a[3] = (__bf16)u[t].w;
            a[4] = (__bf16)v[t].x; a[5] = (__bf16)v[t].y;
            a[6] = (__bf16)v[t].z; a[7] = (__bf16)v[t].w;
            const __bf16* wb = w12t + kb * 32 + q * 8;
            bf16x8 f0 = *(const bf16x8*)(wb + l15 * K1);
            bf16x8 f1 = *(const bf16x8*)(wb + (16 + l15) * K1);
            bf16x8 f2 = *(const bf16x8*)(wb + (32 + l15) * K1);
            bf16x8 f3 = *(const bf16x8*)(wb + (48 + l15) * K1);
            acc0 = __builtin_amdgcn_mfma_f32_16x16x32_bf16(a, f0, acc0, 0, 0, 0);
            acc1 = __builtin_amdgcn_mfma_f32_16x16x32_bf16(a, f1, acc1, 0, 0, 0);
            acc2 = __builtin_amdgcn_mfma_f32_16x16x32_bf16(a, f2, acc2, 0, 0, 0);
            acc3 = __builtin_amdgcn_mfma_f32_16x16x32_bf16(a, f3, acc3, 0, 0, 0);
        }
        #pragma unroll
        for (int r = 0; r < 4; ++r) {
            h1p[wv][q * 4 + r][l15]      = acc0[r];
            h1p[wv][q * 4 + r][16 + l15] = acc1[r];
            h1p[wv][q * 4 + r][32 + l15] = acc2[r];
            h1p[wv][q * 4 + r][48 + l15] = acc3[r];
        }
    }
    __syncthreads();

    // ---------------- phase 3 load machinery (groups of 3 col-tiles, 2-deep)
    const int c0l = wv * 192 + l15;
    bf16x8 F0[2][3], F1[2][3];
    float  pb[2][3][4];

#define LOADG(buf, g)                                                         \
    {                                                                         \
        _Pragma("unroll")                                                     \
        for (int t = 0; t < 3; ++t) {                                         \
            const int col = c0l + ((g) * 3 + t) * 16;                         \
            const __bf16* wr = w3t + col * NH;                                \
            F0[buf][t] = *(const bf16x8*)(wr + q * 8);                        \
            F1[buf][t] = *(const bf16x8*)(wr + 32 + q * 8);                   \
            _Pragma("unroll")                                                 \
            for (int r = 0; r < 4; ++r) pb[buf][t][r] = posb[pbase[r] + col]; \
        }                                                                     \
    }

    bf16x8 a0, a1;

#define COMPG(buf, g)                                                         \
    {                                                                         \
        _Pragma("unroll")                                                     \
        for (int t = 0; t < 3; ++t) {                                         \
            const int col = c0l + ((g) * 3 + t) * 16;                         \
            f32x4 z = {0.f, 0.f, 0.f, 0.f};                                   \
            f32x4 c = __builtin_amdgcn_mfma_f32_16x16x32_bf16(a0, F0[buf][t], z, 0, 0, 0); \
            c = __builtin_amdgcn_mfma_f32_16x16x32_bf16(a1, F1[buf][t], c, 0, 0, 0);       \
            _Pragma("unroll")                                                 \
            for (int r = 0; r < 4; ++r) out[obase[r] + col] = c[r] + pb[buf][t][r];        \
        }                                                                     \
    }

    LOADG(0, 0)   // group-0 loads hide under the phase-2 LDS reduce

    // ---------------- phase 2: reduce partials -> stage-2 A fragments
    {
        f32x4 s0a = {0.f, 0.f, 0.f, 0.f};
        f32x4 s0b = s0a, s1a = s0a, s1b = s0a;
        #pragma unroll
        for (int w = 0; w < 4; ++w) {
            const float* hp = &h1p[w][l15][0];
            s0a += *(const f32x4*)(hp + q * 8);
            s0b += *(const f32x4*)(hp + q * 8 + 4);
            s1a += *(const f32x4*)(hp + 32 + q * 8);
            s1b += *(const f32x4*)(hp + 32 + q * 8 + 4);
        }
        #pragma unroll
        for (int j = 0; j < 4; ++j) {
            a0[j] = (__bf16)s0a[j]; a0[4 + j] = (__bf16)s0b[j];
            a1[j] = (__bf16)s1a[j]; a1[4 + j] = (__bf16)s1b[j];
        }
    }

    // ---------------- phase 3: software-pipelined 4 groups
    LOADG(1, 1)
    COMPG(0, 0)
    LOADG(0, 2)
    COMPG(1, 1)
    LOADG(1, 3)
    COMPG(0, 2)
    COMPG(1, 3)

#undef LOADG
#undef COMPG
}

extern "C" void kernel_launch(void* const* d_in, const int* in_sizes, int n_in,
                              void* d_out, int out_size, void* d_ws, size_t ws_size,
                              hipStream_t stream)
{
    const float* X   = (const float*)d_in[0];
    const float* W1  = (const float*)d_in[1];
    const float* b1  = (const float*)d_in[2];
    const float* W2  = (const float*)d_in[3];
    const float* b2  = (const float*)d_in[4];
    const float* W3  = (const float*)d_in[5];
    const float* b3  = (const float*)d_in[6];
    const float* cls = (const float*)d_in[7];
    const float* pos = (const float*)d_in[8];
    float* out = (float*)d_out;

    char* ws = (char*)d_ws;
    __bf16* w12t = (__bf16*)(ws + W12T_OFF);
    __bf16* w3t  = (__bf16*)(ws + W3T_OFF);
    float*  b12  = (float*)(ws + B12_OFF);
    float*  posb = (float*)(ws + POSB_OFF);

    patchembed_prep1<<<193, 256, 0, stream>>>(W1, W2, b1, b2, w12t, b12);
    patchembed_prep2<<<1167, 256, 0, stream>>>(W3, b3, cls, pos, b12, w3t, posb, out);
    patchembed_main<<<1568, 256, 0, stream>>>(X, w12t, w3t, posb, out);
}

// Round 3
// 189.510 us; speedup vs baseline: 1.0500x; 1.0500x over previous
//
#include <hip/hip_runtime.h>

// PatchEmbeder v4: two-kernel split. v2b/v3 were latency-serialized monoliths
// (Occ 35-48%, VALUBusy <8%, MfmaUtil <2.3%) and two rounds of source-level
// ILP batching were defeated by the compiler (VGPR stayed 40/44). v4 decouples:
//   s1: X[25088,768] @ W12 -> H[25088,64] bf16   (v3 phase1+2, verified code)
//   s2: H @ W3 + posb -> out                      (NO LDS, NO barriers,
//       12544 independent waves = 49/CU -> TLP hides latency instead of ILP)
// W1@W2 collapsed to W12 (exact); b12=b1@W2+b2 folded through W3 into posb.
// H lives in workspace at +802048 (total ws use ~3.9 MB).

#define BATCH 128
#define CH    3
#define NP    196
#define PIX   256          // 16*16
#define K1    768          // CH*PIX
#define NH    64           // collapsed hidden width (W12 cols)
#define EMB   768
#define NROW  (BATCH * NP) // 25088 patch rows

typedef __bf16 bf16x8 __attribute__((ext_vector_type(8)));
typedef float  f32x4  __attribute__((ext_vector_type(4)));

// workspace byte offsets (16B aligned)
#define W12T_OFF 0                       // [64][768] bf16 = 98304
#define W3T_OFF  98304                   // [768][64] bf16 = 98304
#define B12_OFF  196608                  // [64] f32 = 256
#define POSB_OFF 196864                  // [197][768] f32 = 605184
#define H_OFF    802048                  // [25088][64] bf16 = 3211264 -> 4013312

// ---------------------------------------------------------------------------
// prep1: w12t[n][k] = (W1@W2)^T in bf16; b12 = b1@W2 + b2 (f32)
// ---------------------------------------------------------------------------
__global__ __launch_bounds__(256) void patchembed_prep1(
    const float* __restrict__ W1, const float* __restrict__ W2,
    const float* __restrict__ b1, const float* __restrict__ b2,
    __bf16* __restrict__ w12t, float* __restrict__ b12)
{
    const int i = blockIdx.x * 256 + threadIdx.x;
    if (i < NH * K1) {                 // i = n*768 + k
        const int n = i / K1, k = i - n * K1;
        float s = 0.f;
        #pragma unroll
        for (int j = 0; j < 32; ++j) s += W1[k * 32 + j] * W2[j * NH + n];
        w12t[i] = (__bf16)s;
    } else if (i < NH * K1 + NH) {
        const int n = i - NH * K1;
        float s = b2[n];
        #pragma unroll
        for (int j = 0; j < 32; ++j) s += b1[j] * W2[j * NH + n];
        b12[n] = s;
    }
}

// ---------------------------------------------------------------------------
// prep2: w3t transpose; posb[r][c] = pos + (r==0 ? cls : b3 + b12@W3); cls rows
// ---------------------------------------------------------------------------
__global__ __launch_bounds__(256) void patchembed_prep2(
    const float* __restrict__ W3, const float* __restrict__ b3,
    const float* __restrict__ cls, const float* __restrict__ pos,
    const float* __restrict__ b12,
    __bf16* __restrict__ w3t, float* __restrict__ posb, float* __restrict__ out)
{
    const int i = blockIdx.x * 256 + threadIdx.x;
    const int T1 = EMB * NH;           // 49152
    const int T2 = T1 + 197 * EMB;     // 200448
    const int T3 = T2 + BATCH * EMB;   // 298752
    if (i < T1) {                      // w3t[col][kk] = W3[kk][col]
        const int col = i >> 6, kk = i & 63;
        w3t[i] = (__bf16)W3[kk * EMB + col];
    } else if (i < T2) {
        const int j = i - T1;
        const int r = j / EMB, c = j - r * EMB;
        float v = pos[j];
        if (r == 0) {
            v += cls[c];               // row 0 never read by s2; harmless
        } else {
            float s = b3[c];           // fold (b1@W2+b2)@W3 + b3 into the table
            #pragma unroll
            for (int n = 0; n < NH; ++n) s += b12[n] * W3[n * EMB + c];
            v += s;
        }
        posb[j] = v;
    } else if (i < T3) {               // out[b][0][c] = cls + pos[0]
        const int j = i - T2;
        const int b = j / EMB, c = j - b * EMB;
        out[b * (197 * EMB) + c] = cls[c] + pos[c];
    }
}

// ---------------------------------------------------------------------------
// s1: stage-1 mm (x @ W12) -> H bf16. 16 rows/block, 4 waves, K-split 4-way
// (wave wv does ksteps [wv*6, wv*6+6)), f32 partials -> LDS, wave 0 reduces
// and stores H[row][0..63] as two bf16x8 per thread. This is v3's verified
// phase1+2 with the reduce result going to global instead of phase 3.
// MFMA 16x16x32 bf16 layouts (verified m89/m120):
//   A: m = lane&15, k = (lane>>4)*8 + j
//   B: n = lane&15, k = (lane>>4)*8 + j
//   C: col = lane&15, row = (lane>>4)*4 + reg
// ---------------------------------------------------------------------------
__global__ __launch_bounds__(256) void patchembed_s1(
    const float* __restrict__ X,      // [B][C][P][256] fp32
    const __bf16* __restrict__ w12t,  // [64][768]
    __bf16* __restrict__ H)           // [25088][64]
{
    __shared__ __align__(16) float h1p[4][16][68];  // 17408 B

    const int tid  = threadIdx.x;
    const int wv   = tid >> 6;
    const int lane = tid & 63;
    const int l15  = lane & 15;
    const int q    = lane >> 4;
    const int r0   = blockIdx.x * 16;

    // ---------------- phase 1: partial H over K=192 per wave
    {
        const int xrow = r0 + l15;
        const int b = xrow / NP, p = xrow - b * NP;
        const float* xb = X + ((b * CH) * NP + p) * PIX;
        const int kb0 = wv * 6;

        f32x4 acc0 = {0.f, 0.f, 0.f, 0.f};
        f32x4 acc1 = acc0, acc2 = acc0, acc3 = acc0;
        #pragma unroll
        for (int t = 0; t < 6; ++t) {
            const int kb = kb0 + t;
            const float* ptr = xb + (kb >> 3) * (NP * PIX) + (kb & 7) * 32 + q * 8;
            float4 u = *(const float4*)ptr;
            float4 v = *(const float4*)(ptr + 4);
            bf16x8 a;
            a[0] = (__bf16)u.x; a[1] = (__bf16)u.y;
            a[2] = (__bf16)u.z; a[3] = (__bf16)u.w;
            a[4] = (__bf16)v.x; a[5] = (__bf16)v.y;
            a[6] = (__bf16)v.z; a[7] = (__bf16)v.w;
            const __bf16* wb = w12t + kb * 32 + q * 8;
            bf16x8 f0 = *(const bf16x8*)(wb + l15 * K1);
            bf16x8 f1 = *(const bf16x8*)(wb + (16 + l15) * K1);
            bf16x8 f2 = *(const bf16x8*)(wb + (32 + l15) * K1);
            bf16x8 f3 = *(const bf16x8*)(wb + (48 + l15) * K1);
            acc0 = __builtin_amdgcn_mfma_f32_16x16x32_bf16(a, f0, acc0, 0, 0, 0);
            acc1 = __builtin_amdgcn_mfma_f32_16x16x32_bf16(a, f1, acc1, 0, 0, 0);
            acc2 = __builtin_amdgcn_mfma_f32_16x16x32_bf16(a, f2, acc2, 0, 0, 0);
            acc3 = __builtin_amdgcn_mfma_f32_16x16x32_bf16(a, f3, acc3, 0, 0, 0);
        }
        #pragma unroll
        for (int r = 0; r < 4; ++r) {
            h1p[wv][q * 4 + r][l15]      = acc0[r];
            h1p[wv][q * 4 + r][16 + l15] = acc1[r];
            h1p[wv][q * 4 + r][32 + l15] = acc2[r];
            h1p[wv][q * 4 + r][48 + l15] = acc3[r];
        }
    }
    __syncthreads();

    // ---------------- phase 2: wave 0 reduces 4 partials -> H bf16
    if (wv == 0) {
        f32x4 s0a = {0.f, 0.f, 0.f, 0.f};
        f32x4 s0b = s0a, s1a = s0a, s1b = s0a;
        #pragma unroll
        for (int w = 0; w < 4; ++w) {
            const float* hp = &h1p[w][l15][0];
            s0a += *(const f32x4*)(hp + q * 8);
            s0b += *(const f32x4*)(hp + q * 8 + 4);
            s1a += *(const f32x4*)(hp + 32 + q * 8);
            s1b += *(const f32x4*)(hp + 32 + q * 8 + 4);
        }
        bf16x8 a0, a1;
        #pragma unroll
        for (int j = 0; j < 4; ++j) {
            a0[j] = (__bf16)s0a[j]; a0[4 + j] = (__bf16)s0b[j];
            a1[j] = (__bf16)s1a[j]; a1[4 + j] = (__bf16)s1b[j];
        }
        // H[row][k]: row = r0+l15, a0 -> k[q*8..q*8+7], a1 -> k[32+q*8..]
        __bf16* hr = H + (r0 + l15) * NH;
        *(bf16x8*)(hr + q * 8)      = a0;
        *(bf16x8*)(hr + 32 + q * 8) = a1;
    }
}

// ---------------------------------------------------------------------------
// s2: stage-2 mm (H @ W3) + posb -> out. NO LDS, NO barriers. Each wave owns
// 16 rows x 96 cols: wave_id = blk*4+wv; row tile = wave_id>>3, col seg =
// wave_id&7. 12544 waves total (49/CU) -> latency hidden by TLP.
// A-frags reload exactly what s1 stored: a0 = H[r0+l15][q*8..], a1 = +32.
// ---------------------------------------------------------------------------
__global__ __launch_bounds__(256) void patchembed_s2(
    const __bf16* __restrict__ H,     // [25088][64]
    const __bf16* __restrict__ w3t,   // [768][64]
    const float*  __restrict__ posb,  // [197][768]
    float* __restrict__ out)          // [B][197][768]
{
    const int tid  = threadIdx.x;
    const int wv   = tid >> 6;
    const int lane = tid & 63;
    const int l15  = lane & 15;
    const int q    = lane >> 4;

    const int wave_id = blockIdx.x * 4 + wv;
    const int rt = wave_id >> 3;          // 0..1567
    const int cs = wave_id & 7;           // 0..7
    const int r0 = rt * 16;

    const __bf16* hr = H + (r0 + l15) * NH;
    bf16x8 a0 = *(const bf16x8*)(hr + q * 8);
    bf16x8 a1 = *(const bf16x8*)(hr + 32 + q * 8);

    int obase[4], pbase[4];
    #pragma unroll
    for (int r = 0; r < 4; ++r) {
        const int row = r0 + q * 4 + r;
        const int b = row / NP, p = row - b * NP;
        obase[r] = (b * 197 + p + 1) * EMB;
        pbase[r] = (p + 1) * EMB;
    }

    const int c0 = cs * 96 + l15;
    #pragma unroll
    for (int t = 0; t < 6; ++t) {
        const int col = c0 + t * 16;
        const __bf16* wr = w3t + col * NH;
        bf16x8 f0 = *(const bf16x8*)(wr + q * 8);
        bf16x8 f1 = *(const bf16x8*)(wr + 32 + q * 8);
        float pb0 = posb[pbase[0] + col];
        float pb1 = posb[pbase[1] + col];
        float pb2 = posb[pbase[2] + col];
        float pb3 = posb[pbase[3] + col];
        f32x4 z = {0.f, 0.f, 0.f, 0.f};
        f32x4 c = __builtin_amdgcn_mfma_f32_16x16x32_bf16(a0, f0, z, 0, 0, 0);
        c       = __builtin_amdgcn_mfma_f32_16x16x32_bf16(a1, f1, c, 0, 0, 0);
        out[obase[0] + col] = c[0] + pb0;
        out[obase[1] + col] = c[1] + pb1;
        out[obase[2] + col] = c[2] + pb2;
        out[obase[3] + col] = c[3] + pb3;
    }
}

extern "C" void kernel_launch(void* const* d_in, const int* in_sizes, int n_in,
                              void* d_out, int out_size, void* d_ws, size_t ws_size,
                              hipStream_t stream)
{
    const float* X   = (const float*)d_in[0];
    const float* W1  = (const float*)d_in[1];
    const float* b1  = (const float*)d_in[2];
    const float* W2  = (const float*)d_in[3];
    const float* b2  = (const float*)d_in[4];
    const float* W3  = (const float*)d_in[5];
    const float* b3  = (const float*)d_in[6];
    const float* cls = (const float*)d_in[7];
    const float* pos = (const float*)d_in[8];
    float* out = (float*)d_out;

    char* ws = (char*)d_ws;
    __bf16* w12t = (__bf16*)(ws + W12T_OFF);
    __bf16* w3t  = (__bf16*)(ws + W3T_OFF);
    float*  b12  = (float*)(ws + B12_OFF);
    float*  posb = (float*)(ws + POSB_OFF);
    __bf16* H    = (__bf16*)(ws + H_OFF);

    patchembed_prep1<<<193, 256, 0, stream>>>(W1, W2, b1, b2, w12t, b12);
    patchembed_prep2<<<1167, 256, 0, stream>>>(W3, b3, cls, pos, b12, w3t, posb, out);
    patchembed_s1<<<NROW / 16, 256, 0, stream>>>(X, w12t, H);         // 1568
    patchembed_s2<<<NROW / 16 * 2, 256, 0, stream>>>(H, w3t, posb, out); // 3136
}